// Round 12
// baseline (231.769 us; speedup 1.0000x reference)
//
#include <hip/hip_runtime.h>
#include <hip/hip_cooperative_groups.h>

namespace cg = cooperative_groups;

// SpMM: out[i,d] = sum_{e: rows[e]==i} vals[e] * x[cols[e], d]
// N=100000 nodes, E=1600000 edges, DIM=32, fp32.
//
// v13: single COOPERATIVE kernel = phase0 zero + phase1 scatter + phase2 sort/gather.
//  v12 post-mortem: rank-from-hist gained +0.9us only -> LDS atomics off the
//  critical path. Remaining controllable: 2 launch gaps + memset dispatch
//  (~6-8us) and scatter's 15.6 waves/CU latency exposure.
//  v13 geometry: 391 blocks x 1024 threads, __launch_bounds__(1024,8)
//  (8 waves/SIMD -> 2 blocks/CU -> coop capacity 512 >= 391; VGPR<=64).
//   phase0: grid zeros gcnt/ocount (memset dispatch deleted); grid.sync
//   phase1: v12 scatter at 4093 edges/block (EPT=4, 24 waves/CU); grid.sync
//   phase2: v12 sort_gather verbatim, bc = blockIdx (1:1 buckets); overflow tail.
//  Coop launch error -> verified v12 3-dispatch fallback path.
//
//  ws layout (~21.1 MB):
//   [0     .. 64)     : ocount
//   [64    .. 25088)  : gcnt, NBC x 64B-padded int
//   [25088 .. 287K)   : overflow, OCAP x int4 {r,c,valbits,_}
//   [~287K .. ~21.1M) : region, NBC x CAPC x int2 {(lrow<<17)|col, valbits}

#define N_NODES 100000
#define N_EDGES 1600000
#define DIM 32

#define CBR    256
#define NBC    ((N_NODES + CBR - 1) / CBR)   // 391
#define CHUNK  8
#define CAPC   6656
#define OCAP   16384

#define FB_THREADS 1024
#define EPB1       4093                      // ceil(E / 391)
#define EPT1       4                         // ceil(4093/1024)
#define EPT2       7                         // ceil(CAPC/1024)

// v12 fallback scatter geometry
#define SC_BLOCKS   500
#define SC_THREADS  512
#define EPB         3200
#define EPT         7

#define OFF_GCNT    64
#define OFF_OVER    (OFF_GCNT + NBC * 64)
#define OFF_REGION  (((OFF_OVER + OCAP * 16) + 255) & ~255)
#define WS_NEEDED   ((size_t)OFF_REGION + (size_t)NBC * CAPC * 8)

// ---------- fallback: original verified kernel (thread per (edge,dim)) ----------
__global__ __launch_bounds__(256) void spmm_atomic_kernel(
    const int* __restrict__ rows,
    const int* __restrict__ cols,
    const float* __restrict__ vals,
    const float* __restrict__ x,
    float* __restrict__ out)
{
    const long long idx = (long long)blockIdx.x * blockDim.x + threadIdx.x;
    const long long total = (long long)N_EDGES * DIM;
    if (idx >= total) return;
    const int e = (int)(idx >> 5);
    const int d = (int)(idx & 31);
    const int r   = rows[e];
    const int c   = cols[e];
    const float v = vals[e];
    atomicAdd(&out[(long long)r * DIM + d], v * x[(long long)c * DIM + d]);
}

// ================= v13: single cooperative kernel =================
__global__ __launch_bounds__(FB_THREADS, 8) void spmm_fused(
    const int* __restrict__ rows,
    const int* __restrict__ cols,
    const float* __restrict__ vals,
    int* __restrict__ gcnt,          // NBC cursors, 64B-padded (index *16)
    int2* __restrict__ region,       // NBC x CAPC
    int* __restrict__ ocount,
    int4* __restrict__ overflow,
    const float* __restrict__ x,
    float* __restrict__ out)
{
    __shared__ int2 buf[CAPC];       // 53.2 KB: stage (ph1) / sorted (ph2)
    __shared__ int  hist[NBC];
    __shared__ int  aux1[NBC];       // lstart (ph1) / startx inclusive (ph2)
    __shared__ int  aux2[NBC];       // gbase  (ph1) / excl start (ph2)
    __shared__ int  wsum[16];

    const int tid  = threadIdx.x;
    const int bid  = blockIdx.x;
    const int lane = tid & 63;
    const int wv   = tid >> 6;
    cg::grid_group grid = cg::this_grid();

    // ---- phase 0: zero cursors (replaces the memset dispatch) ----
    for (int i = bid * FB_THREADS + tid; i < NBC * 16; i += NBC * FB_THREADS)
        gcnt[i] = 0;
    if (bid == 0 && tid == 0) *ocount = 0;
    grid.sync();

    // ---- phase 1: register-staged WC scatter (v12, 391 blocks) ----
    if (tid < NBC) hist[tid] = 0;
    __syncthreads();

    const int ebase = bid * EPB1;
    int en_x[EPT1], en_y[EPT1], eb[EPT1], rk[EPT1];
    #pragma unroll
    for (int i = 0; i < EPT1; ++i) {
        const int o = i * FB_THREADS + tid;
        const int e = ebase + o;
        eb[i] = -1; en_x[i] = 0; en_y[i] = 0; rk[i] = 0;
        if (o < EPB1 && e < N_EDGES) {
            const int r = rows[e];
            eb[i]   = r >> 8;
            en_x[i] = ((r & 255) << 17) | cols[e];
            en_y[i] = __float_as_int(vals[e]);
            rk[i]   = atomicAdd(&hist[eb[i]], 1);   // dense per-bucket rank
        }
    }
    __syncthreads();

    // 2-level shfl scan over NBC=391 (16 waves)
    {
        const int myh = (tid < NBC) ? hist[tid] : 0;
        int s = myh;
        #pragma unroll
        for (int off = 1; off < 64; off <<= 1) {
            const int t = __shfl_up(s, off, 64);
            if (lane >= off) s += t;
        }
        if (lane == 63) wsum[wv] = s;
        __syncthreads();
        if (wv == 0) {
            const int t = (lane < 16) ? wsum[lane] : 0;
            int ss = t;
            #pragma unroll
            for (int off = 1; off < 16; off <<= 1) {
                const int u = __shfl_up(ss, off, 64);
                if (lane >= off) ss += u;
            }
            if (lane < 16) wsum[lane] = ss - t;
        }
        __syncthreads();
        if (tid < NBC) {
            aux1[tid] = s + wsum[wv] - myh;          // lstart (exclusive)
            const int pad = (myh + 7) & ~7;
            aux2[tid] = pad ? atomicAdd(&gcnt[tid * 16], pad) : 0;
        }
    }
    __syncthreads();

    // placement: pure LDS write at lstart + rank
    #pragma unroll
    for (int i = 0; i < EPT1; ++i) {
        if (eb[i] >= 0)
            buf[aux1[eb[i]] + rk[i]] = make_int2(en_x[i], en_y[i]);
    }
    __syncthreads();

    // flush: full 64B lines only (sentinel pad), one-lane bursts (v7-proven WC)
    for (int bc = tid; bc < NBC; bc += FB_THREADS) {
        const int n  = hist[bc];
        const int ls = aux1[bc];
        const int gb = aux2[bc];
        const int nch = (n + 7) >> 3;
        for (int j = 0; j < nch; ++j) {
            const int gpos = gb + j * CHUNK;
            if (gpos + CHUNK <= CAPC) {
                int2* dst = region + (size_t)bc * CAPC + gpos;
                #pragma unroll
                for (int q = 0; q < CHUNK; ++q) {
                    const int k = j * CHUNK + q;
                    dst[q] = (k < n) ? buf[ls + k] : make_int2(-1, 0);
                }
            } else {
                for (int q = 0; q < CHUNK; ++q) {
                    const int k = j * CHUNK + q;
                    if (k < n) {
                        const int2 t = buf[ls + k];
                        const int op = atomicAdd(ocount, 1);
                        if (op < OCAP)
                            overflow[op] = make_int4((bc << 8) | (t.x >> 17),
                                                     t.x & 0x1FFFF, t.y, 0);
                    }
                }
            }
        }
    }

    grid.sync();

    // ---- phase 2: per-bucket sort + gather (v12 shape, bc = bid) ----
    const int bc = bid;
    int n = gcnt[bc * 16]; if (n > CAPC) n = CAPC;
    const int2* __restrict__ slice = region + (size_t)bc * CAPC;

    if (tid < CBR) hist[tid] = 0;
    __syncthreads();

    int ex[EPT2], ey[EPT2], rq[EPT2];
    #pragma unroll
    for (int i = 0; i < EPT2; ++i) {
        const int k = i * FB_THREADS + tid;
        ex[i] = -1; ey[i] = 0; rq[i] = 0;
        if (k < n) {
            const int2 e = slice[k];
            ex[i] = e.x; ey[i] = e.y;
            if (e.x >= 0) rq[i] = atomicAdd(&hist[e.x >> 17], 1);
        }
    }
    __syncthreads();

    // shfl scan over 256 hist values (waves 0..3)
    int h = 0, incl = 0;
    if (tid < CBR) {
        h = hist[tid];
        int s = h;
        #pragma unroll
        for (int off = 1; off < 64; off <<= 1) {
            const int t = __shfl_up(s, off, 64);
            if (lane >= off) s += t;
        }
        incl = s;
        if (lane == 63) wsum[wv] = s;
    }
    __syncthreads();
    if (wv == 0) {
        const int t = (lane < 4) ? wsum[lane] : 0;
        int ss = t;
        #pragma unroll
        for (int off = 1; off < 4; off <<= 1) {
            const int u = __shfl_up(ss, off, 64);
            if (lane >= off) ss += u;
        }
        if (lane < 4) wsum[lane] = ss - t;
    }
    __syncthreads();
    if (tid < CBR) {
        incl += wsum[wv];
        aux1[tid] = incl;          // inclusive
        aux2[tid] = incl - h;      // exclusive
    }
    __syncthreads();

    #pragma unroll
    for (int i = 0; i < EPT2; ++i) {
        if (ex[i] >= 0)
            buf[aux2[ex[i] >> 17] + rq[i]] = make_int2(ex[i] & 0x1FFFF, ey[i]);
    }
    __syncthreads();

    // gather: wave w -> rows w*16 .. w*16+15; chain = x loads only
    const int wid = tid >> 6;
    const int eg  = lane >> 3;
    const int d4  = lane & 7;

    #pragma unroll
    for (int i = 0; i < 16; ++i) {
        const int lrow = wid * 16 + i;
        const int cnt  = hist[lrow];
        const int st   = aux1[lrow] - cnt;

        float4 acc = make_float4(0.f, 0.f, 0.f, 0.f);
        for (int k0 = 0; k0 < cnt; k0 += 16) {
            const int ka = k0 + eg;
            const int kb = ka + 8;
            const int2 ea  = (ka < cnt) ? buf[st + ka] : make_int2(0, 0);
            const int2 eb2 = (kb < cnt) ? buf[st + kb] : make_int2(0, 0);
            const float va = __int_as_float(ea.y);
            const float vb = __int_as_float(eb2.y);
            const float4 xa = *(const float4*)&x[ea.x  * DIM + d4 * 4];
            const float4 xb = *(const float4*)&x[eb2.x * DIM + d4 * 4];
            acc.x = fmaf(va, xa.x, acc.x);  acc.y = fmaf(va, xa.y, acc.y);
            acc.z = fmaf(va, xa.z, acc.z);  acc.w = fmaf(va, xa.w, acc.w);
            acc.x = fmaf(vb, xb.x, acc.x);  acc.y = fmaf(vb, xb.y, acc.y);
            acc.z = fmaf(vb, xb.z, acc.z);  acc.w = fmaf(vb, xb.w, acc.w);
        }
        #pragma unroll
        for (int m = 8; m < 64; m <<= 1) {
            acc.x += __shfl_xor(acc.x, m, 64);
            acc.y += __shfl_xor(acc.y, m, 64);
            acc.z += __shfl_xor(acc.z, m, 64);
            acc.w += __shfl_xor(acc.w, m, 64);
        }
        const int r = bc * CBR + lrow;
        if (eg == 0 && r < N_NODES)
            *(float4*)&out[r * DIM + d4 * 4] = acc;
    }

    // overflow tail (normally empty): barrier drains out stores first
    __syncthreads();
    int on = *ocount;
    if (on > 0) {
        if (on > OCAP) on = OCAP;
        for (int k = tid; k < on; k += FB_THREADS) {
            const int4 t = overflow[k];
            if ((t.x >> 8) == bc) {
                const float v = __int_as_float(t.z);
                const float* __restrict__ xr = x + (long long)t.y * DIM;
                float* orow = out + (long long)t.x * DIM;
                for (int d = 0; d < DIM; ++d)
                    atomicAdd(&orow[d], v * xr[d]);
            }
        }
    }
}

// ================= v12 fallback kernels (verified) =================
__global__ __launch_bounds__(SC_THREADS) void spmm_scatter_ws(
    const int* __restrict__ rows, const int* __restrict__ cols,
    const float* __restrict__ vals, int* __restrict__ gcnt,
    int2* __restrict__ region, int* __restrict__ ocount, int4* __restrict__ overflow)
{
    __shared__ int2 stage[EPB];
    __shared__ int  hist[NBC];
    __shared__ int  lstart[NBC];
    __shared__ int  gbase[NBC];
    __shared__ int  wsum[8];

    const int tid = threadIdx.x;
    const int ebase = blockIdx.x * EPB;
    if (tid < NBC) hist[tid] = 0;
    __syncthreads();

    int en_x[EPT], en_y[EPT], eb[EPT], rk[EPT];
    #pragma unroll
    for (int i = 0; i < EPT; ++i) {
        const int o = i * SC_THREADS + tid;
        eb[i] = -1; en_x[i] = 0; en_y[i] = 0; rk[i] = 0;
        if (o < EPB) {
            const int e = ebase + o;
            const int r = rows[e];
            eb[i]   = r >> 8;
            en_x[i] = ((r & 255) << 17) | cols[e];
            en_y[i] = __float_as_int(vals[e]);
            rk[i]   = atomicAdd(&hist[eb[i]], 1);
        }
    }
    __syncthreads();

    const int lane = tid & 63, wv = tid >> 6;
    const int myh = (tid < NBC) ? hist[tid] : 0;
    int s = myh;
    #pragma unroll
    for (int off = 1; off < 64; off <<= 1) { const int t = __shfl_up(s, off, 64); if (lane >= off) s += t; }
    if (lane == 63) wsum[wv] = s;
    __syncthreads();
    if (wv == 0) {
        const int t = (lane < 8) ? wsum[lane] : 0;
        int ss = t;
        #pragma unroll
        for (int off = 1; off < 8; off <<= 1) { const int u = __shfl_up(ss, off, 64); if (lane >= off) ss += u; }
        if (lane < 8) wsum[lane] = ss - t;
    }
    __syncthreads();
    if (tid < NBC) {
        lstart[tid] = s + wsum[wv] - myh;
        const int pad = (myh + 7) & ~7;
        gbase[tid] = pad ? atomicAdd(&gcnt[tid * 16], pad) : 0;
    }
    __syncthreads();

    #pragma unroll
    for (int i = 0; i < EPT; ++i)
        if (eb[i] >= 0) stage[lstart[eb[i]] + rk[i]] = make_int2(en_x[i], en_y[i]);
    __syncthreads();

    for (int bc = tid; bc < NBC; bc += SC_THREADS) {
        const int n = hist[bc], ls = lstart[bc], gb = gbase[bc];
        const int nch = (n + 7) >> 3;
        for (int j = 0; j < nch; ++j) {
            const int gpos = gb + j * CHUNK;
            if (gpos + CHUNK <= CAPC) {
                int2* dst = region + (size_t)bc * CAPC + gpos;
                #pragma unroll
                for (int q = 0; q < CHUNK; ++q) {
                    const int k = j * CHUNK + q;
                    dst[q] = (k < n) ? stage[ls + k] : make_int2(-1, 0);
                }
            } else {
                for (int q = 0; q < CHUNK; ++q) {
                    const int k = j * CHUNK + q;
                    if (k < n) {
                        const int2 t = stage[ls + k];
                        const int op = atomicAdd(ocount, 1);
                        if (op < OCAP)
                            overflow[op] = make_int4((bc << 8) | (t.x >> 17), t.x & 0x1FFFF, t.y, 0);
                    }
                }
            }
        }
    }
}

__global__ __launch_bounds__(FB_THREADS) void spmm_sort_gather(
    const int* __restrict__ gcnt, const int2* __restrict__ region,
    const int* __restrict__ ocount, const int4* __restrict__ overflow,
    const float* __restrict__ x, float* __restrict__ out)
{
    __shared__ int2 srt[CAPC];
    __shared__ int  hist[CBR];
    __shared__ int  startx[CBR];
    __shared__ int  excl_s[CBR];
    __shared__ int  wsum[4];

    const int bc = blockIdx.x, tid = threadIdx.x;
    int n = gcnt[bc * 16]; if (n > CAPC) n = CAPC;
    const int2* __restrict__ slice = region + (size_t)bc * CAPC;

    if (tid < CBR) hist[tid] = 0;
    __syncthreads();

    int ex[EPT2], ey[EPT2], rk[EPT2];
    #pragma unroll
    for (int i = 0; i < EPT2; ++i) {
        const int k = i * FB_THREADS + tid;
        ex[i] = -1; ey[i] = 0; rk[i] = 0;
        if (k < n) {
            const int2 e = slice[k];
            ex[i] = e.x; ey[i] = e.y;
            if (e.x >= 0) rk[i] = atomicAdd(&hist[e.x >> 17], 1);
        }
    }
    __syncthreads();

    const int lane = tid & 63, wv = tid >> 6;
    int h = 0, incl = 0;
    if (tid < CBR) {
        h = hist[tid];
        int s = h;
        #pragma unroll
        for (int off = 1; off < 64; off <<= 1) { const int t = __shfl_up(s, off, 64); if (lane >= off) s += t; }
        incl = s;
        if (lane == 63) wsum[wv] = s;
    }
    __syncthreads();
    if (wv == 0) {
        const int t = (lane < 4) ? wsum[lane] : 0;
        int ss = t;
        #pragma unroll
        for (int off = 1; off < 4; off <<= 1) { const int u = __shfl_up(ss, off, 64); if (lane >= off) ss += u; }
        if (lane < 4) wsum[lane] = ss - t;
    }
    __syncthreads();
    if (tid < CBR) { incl += wsum[wv]; startx[tid] = incl; excl_s[tid] = incl - h; }
    __syncthreads();

    #pragma unroll
    for (int i = 0; i < EPT2; ++i)
        if (ex[i] >= 0) srt[excl_s[ex[i] >> 17] + rk[i]] = make_int2(ex[i] & 0x1FFFF, ey[i]);
    __syncthreads();

    const int wid = tid >> 6, eg = lane >> 3, d4 = lane & 7;
    #pragma unroll
    for (int i = 0; i < 16; ++i) {
        const int lrow = wid * 16 + i;
        const int cnt = hist[lrow];
        const int st  = startx[lrow] - cnt;
        float4 acc = make_float4(0.f, 0.f, 0.f, 0.f);
        for (int k0 = 0; k0 < cnt; k0 += 16) {
            const int ka = k0 + eg, kb = ka + 8;
            const int2 ea  = (ka < cnt) ? srt[st + ka] : make_int2(0, 0);
            const int2 eb2 = (kb < cnt) ? srt[st + kb] : make_int2(0, 0);
            const float va = __int_as_float(ea.y);
            const float vb = __int_as_float(eb2.y);
            const float4 xa = *(const float4*)&x[ea.x  * DIM + d4 * 4];
            const float4 xb = *(const float4*)&x[eb2.x * DIM + d4 * 4];
            acc.x = fmaf(va, xa.x, acc.x);  acc.y = fmaf(va, xa.y, acc.y);
            acc.z = fmaf(va, xa.z, acc.z);  acc.w = fmaf(va, xa.w, acc.w);
            acc.x = fmaf(vb, xb.x, acc.x);  acc.y = fmaf(vb, xb.y, acc.y);
            acc.z = fmaf(vb, xb.z, acc.z);  acc.w = fmaf(vb, xb.w, acc.w);
        }
        #pragma unroll
        for (int m = 8; m < 64; m <<= 1) {
            acc.x += __shfl_xor(acc.x, m, 64);
            acc.y += __shfl_xor(acc.y, m, 64);
            acc.z += __shfl_xor(acc.z, m, 64);
            acc.w += __shfl_xor(acc.w, m, 64);
        }
        const int r = bc * CBR + lrow;
        if (eg == 0 && r < N_NODES)
            *(float4*)&out[r * DIM + d4 * 4] = acc;
    }

    __syncthreads();
    int on = *ocount;
    if (on > 0) {
        if (on > OCAP) on = OCAP;
        for (int k = tid; k < on; k += FB_THREADS) {
            const int4 t = overflow[k];
            if ((t.x >> 8) == bc) {
                const float v = __int_as_float(t.z);
                const float* __restrict__ xr = x + (long long)t.y * DIM;
                float* orow = out + (long long)t.x * DIM;
                for (int d = 0; d < DIM; ++d) atomicAdd(&orow[d], v * xr[d]);
            }
        }
    }
}

extern "C" void kernel_launch(void* const* d_in, const int* in_sizes, int n_in,
                              void* d_out, int out_size, void* d_ws, size_t ws_size,
                              hipStream_t stream) {
    const int*   A_rows = (const int*)d_in[0];
    const int*   A_cols = (const int*)d_in[1];
    const float* A_vals = (const float*)d_in[2];
    const float* x      = (const float*)d_in[3];
    float*       out    = (float*)d_out;

    if (d_ws == nullptr || ws_size < WS_NEEDED) {
        hipMemsetAsync(out, 0, (size_t)out_size * sizeof(float), stream);
        const long long total = (long long)N_EDGES * DIM;
        const int block = 256;
        const long long grid = (total + block - 1) / block;
        spmm_atomic_kernel<<<(dim3)(unsigned)grid, block, 0, stream>>>(
            A_rows, A_cols, A_vals, x, out);
        return;
    }

    char* ws = (char*)d_ws;
    int*  ocount   = (int*)ws;
    int*  gcnt     = (int*)(ws + OFF_GCNT);
    int4* overflow = (int4*)(ws + OFF_OVER);
    int2* region   = (int2*)(ws + OFF_REGION);

    // ---- v13: one cooperative launch (zeroing done in-kernel) ----
    void* kargs[] = { (void*)&A_rows, (void*)&A_cols, (void*)&A_vals,
                      (void*)&gcnt, (void*)&region, (void*)&ocount,
                      (void*)&overflow, (void*)&x, (void*)&out };
    hipError_t err = hipLaunchCooperativeKernel(
        (const void*)spmm_fused, dim3(NBC), dim3(FB_THREADS), kargs, 0, stream);

    if (err != hipSuccess) {
        // fallback: verified v12 three-dispatch path
        hipMemsetAsync(ws, 0, OFF_OVER, stream);
        spmm_scatter_ws<<<SC_BLOCKS, SC_THREADS, 0, stream>>>(
            A_rows, A_cols, A_vals, gcnt, region, ocount, overflow);
        spmm_sort_gather<<<NBC, FB_THREADS, 0, stream>>>(
            gcnt, region, ocount, overflow, x, out);
    }
}

// Round 13
// 135.534 us; speedup vs baseline: 1.7101x; 1.7101x over previous
//
#include <hip/hip_runtime.h>

// SpMM: out[i,d] = sum_{e: rows[e]==i} vals[e] * x[cols[e], d]
// N=100000 nodes, E=1600000 edges, DIM=32, fp32.
//
// v14: v12 skeleton (3 dispatches, coop REVERTED) + shuffle-free gather.
//  v13 post-mortem: cooperative fusion cost ~90us in grid.sync (device-scope
//  release/acquire across 8 non-coherent XCD L2s + 391-block spin; FETCH 90MB
//  of post-sync refetches). Reverted per pre-commitment.
//  v14 change: gather lane mapping lane=(row8, d4) -> each lane owns
//  out[r][d4*4..+3] fully: serial entry loop (LDS broadcast reads, unroll-4,
//  4 float4 x-loads in flight/lane), register acc, ONE coalesced float4
//  store. Deletes the 12 ds_bpermute (~360cy serial) per-row reduce tail of
//  v12 (~6K cy/wave). 16 waves x 8 rows = 128 rows/pass, 2 passes.
//    pass0 memset (25KB)   pass1 scatter (v8 WC, unchanged)
//    pass2 fused sort+gather+overflow (shuffle-free gather)
//
//  ws layout (~21.1 MB):
//   [0     .. 64)     : ocount
//   [64    .. 25088)  : gcnt, NBC x 64B-padded int
//   [25088 .. 287K)   : overflow, OCAP x int4 {r,c,valbits,_}
//   [~287K .. ~21.1M) : region, NBC x CAPC x int2 {(lrow<<17)|col, valbits}

#define N_NODES 100000
#define N_EDGES 1600000
#define DIM 32

#define CBR    256                         // rows per coarse bucket
#define NBC    ((N_NODES + CBR - 1) / CBR) // 391
#define CHUNK  8                           // 8 x int2 = 64B line
#define CAPC   6656                        // entries/bucket (mean ~5751 incl pad, +8 sigma)
#define OCAP   16384

#define SC_BLOCKS   500
#define SC_THREADS  512
#define EPB         3200                   // edges per block: 500*3200 = 1.6M exactly
#define EPT         7                      // ceil(3200/512)

#define SG_THREADS  1024
#define SG_EPT      7                      // ceil(CAPC/1024)

#define OFF_GCNT    64
#define OFF_OVER    (OFF_GCNT + NBC * 64)                     // 25088
#define OFF_REGION  (((OFF_OVER + OCAP * 16) + 255) & ~255)
#define WS_NEEDED   ((size_t)OFF_REGION + (size_t)NBC * CAPC * 8)

// ---------- fallback: original verified kernel (thread per (edge,dim)) ----------
__global__ __launch_bounds__(256) void spmm_atomic_kernel(
    const int* __restrict__ rows,
    const int* __restrict__ cols,
    const float* __restrict__ vals,
    const float* __restrict__ x,
    float* __restrict__ out)
{
    const long long idx = (long long)blockIdx.x * blockDim.x + threadIdx.x;
    const long long total = (long long)N_EDGES * DIM;
    if (idx >= total) return;

    const int e = (int)(idx >> 5);
    const int d = (int)(idx & 31);

    const int r   = rows[e];
    const int c   = cols[e];
    const float v = vals[e];

    const float xv = x[(long long)c * DIM + d];
    atomicAdd(&out[(long long)r * DIM + d], v * xv);
}

// ---------- pass 1: register-staged WC scatter, single LDS-atomic pass (v12) ----------
__global__ __launch_bounds__(SC_THREADS) void spmm_scatter_ws(
    const int* __restrict__ rows,
    const int* __restrict__ cols,
    const float* __restrict__ vals,
    int* __restrict__ gcnt,          // NBC cursors, 64B-padded (index *16)
    int2* __restrict__ region,       // NBC x CAPC
    int* __restrict__ ocount,
    int4* __restrict__ overflow)
{
    __shared__ int2 stage[EPB];      // 25.6 KB, bucket-contiguous staging
    __shared__ int  hist[NBC];
    __shared__ int  lstart[NBC];     // LDS segment start per bucket (exclusive)
    __shared__ int  gbase[NBC];      // global reservation per bucket
    __shared__ int  wsum[8];         // per-wave scan sums

    const int tid   = threadIdx.x;
    const int ebase = blockIdx.x * EPB;

    if (tid < NBC) hist[tid] = 0;
    __syncthreads();

    // load edges into registers + histogram; KEEP the atomic's return = rank
    int en_x[EPT], en_y[EPT], eb[EPT], rk[EPT];
    #pragma unroll
    for (int i = 0; i < EPT; ++i) {
        const int o = i * SC_THREADS + tid;
        eb[i] = -1; en_x[i] = 0; en_y[i] = 0; rk[i] = 0;
        if (o < EPB) {
            const int e = ebase + o;
            const int r = rows[e];
            eb[i]   = r >> 8;
            en_x[i] = ((r & 255) << 17) | cols[e];
            en_y[i] = __float_as_int(vals[e]);
            rk[i]   = atomicAdd(&hist[eb[i]], 1);   // dense per-bucket rank
        }
    }
    __syncthreads();

    // 2-level shfl scan over NBC (padded to 512): 2 barriers
    const int lane = tid & 63;
    const int wv   = tid >> 6;
    const int myh  = (tid < NBC) ? hist[tid] : 0;
    int s = myh;
    #pragma unroll
    for (int off = 1; off < 64; off <<= 1) {
        const int t = __shfl_up(s, off, 64);
        if (lane >= off) s += t;
    }
    if (lane == 63) wsum[wv] = s;
    __syncthreads();
    if (wv == 0) {
        const int t = (lane < 8) ? wsum[lane] : 0;
        int ss = t;
        #pragma unroll
        for (int off = 1; off < 8; off <<= 1) {
            const int u = __shfl_up(ss, off, 64);
            if (lane >= off) ss += u;
        }
        if (lane < 8) wsum[lane] = ss - t;   // exclusive wave offset
    }
    __syncthreads();
    if (tid < NBC) {
        lstart[tid] = s + wsum[wv] - myh;
        const int pad = (myh + 7) & ~7;
        // ONE reservation per (block,bucket); 64B-padded counter -> no line contention
        gbase[tid] = pad ? atomicAdd(&gcnt[tid * 16], pad) : 0;
    }
    __syncthreads();

    // placement: PURE LDS write at lstart + rank
    #pragma unroll
    for (int i = 0; i < EPT; ++i) {
        if (eb[i] >= 0)
            stage[lstart[eb[i]] + rk[i]] = make_int2(en_x[i], en_y[i]);
    }
    __syncthreads();

    // flush: full 64B lines only (sentinel pad), one-lane bursts (v7-proven WC)
    for (int bc = tid; bc < NBC; bc += SC_THREADS) {
        const int n   = hist[bc];
        const int ls  = lstart[bc];
        const int gb  = gbase[bc];
        const int nch = (n + 7) >> 3;
        for (int jch = 0; jch < nch; ++jch) {
            const int gpos = gb + jch * CHUNK;
            if (gpos + CHUNK <= CAPC) {
                int2* dst = region + (size_t)bc * CAPC + gpos;
                #pragma unroll
                for (int j = 0; j < CHUNK; ++j) {
                    const int k = jch * CHUNK + j;
                    dst[j] = (k < n) ? stage[ls + k] : make_int2(-1, 0);
                }
            } else {
                // capacity overflow (rare): spill real entries
                for (int j = 0; j < CHUNK; ++j) {
                    const int k = jch * CHUNK + j;
                    if (k < n) {
                        const int2 t = stage[ls + k];
                        const int op = atomicAdd(ocount, 1);
                        if (op < OCAP)
                            overflow[op] = make_int4((bc << 8) | (t.x >> 17),
                                                     t.x & 0x1FFFF, t.y, 0);
                    }
                }
            }
        }
    }
}

// ---------- pass 2: FUSED per-bucket sort + SHUFFLE-FREE gather + overflow ----------
__global__ __launch_bounds__(SG_THREADS) void spmm_sort_gather(
    const int* __restrict__ gcnt,
    const int2* __restrict__ region,
    const int* __restrict__ ocount,
    const int4* __restrict__ overflow,
    const float* __restrict__ x,
    float* __restrict__ out)
{
    __shared__ int2 srt[CAPC];         // 53.2 KB: (col, valbits) row-contiguous
    __shared__ int  hist[CBR];
    __shared__ int  startx[CBR];       // inclusive scan
    __shared__ int  excl_s[CBR];       // exclusive starts
    __shared__ int  wsum[4];

    const int bc  = blockIdx.x;
    const int tid = threadIdx.x;

    int n = gcnt[bc * 16]; if (n > CAPC) n = CAPC;   // written region = [0, min(gcnt,CAPC))
    const int2* __restrict__ slice = region + (size_t)bc * CAPC;

    if (tid < CBR) hist[tid] = 0;
    __syncthreads();

    // register-stage the slice (single region read) + histogram WITH rank capture
    int ex[SG_EPT], ey[SG_EPT], rk[SG_EPT];
    #pragma unroll
    for (int i = 0; i < SG_EPT; ++i) {
        const int k = i * SG_THREADS + tid;
        ex[i] = -1; ey[i] = 0; rk[i] = 0;
        if (k < n) {
            const int2 e = slice[k];
            ex[i] = e.x; ey[i] = e.y;
            if (e.x >= 0) rk[i] = atomicAdd(&hist[e.x >> 17], 1);
        }
    }
    __syncthreads();

    // shfl scan over 256 hist values (waves 0..3 exactly cover tid<256)
    const int lane = tid & 63;
    const int wv   = tid >> 6;
    int h = 0, incl = 0;
    if (tid < CBR) {
        h = hist[tid];
        int s = h;
        #pragma unroll
        for (int off = 1; off < 64; off <<= 1) {
            const int t = __shfl_up(s, off, 64);
            if (lane >= off) s += t;
        }
        incl = s;
        if (lane == 63) wsum[wv] = s;
    }
    __syncthreads();
    if (wv == 0) {
        const int t = (lane < 4) ? wsum[lane] : 0;
        int ss = t;
        #pragma unroll
        for (int off = 1; off < 4; off <<= 1) {
            const int u = __shfl_up(ss, off, 64);
            if (lane >= off) ss += u;
        }
        if (lane < 4) wsum[lane] = ss - t;   // exclusive wave offset
    }
    __syncthreads();
    if (tid < CBR) {
        incl += wsum[wv];
        startx[tid] = incl;
        excl_s[tid] = incl - h;
    }
    __syncthreads();

    // placement: PURE LDS write at excl + rank
    #pragma unroll
    for (int i = 0; i < SG_EPT; ++i) {
        if (ex[i] >= 0)
            srt[excl_s[ex[i] >> 17] + rk[i]] = make_int2(ex[i] & 0x1FFFF, ey[i]);
    }
    __syncthreads();

    // gather: lane = (row-octet, d4); each lane owns out[r][d4*4..+3] fully.
    // No cross-lane reduce. 16 waves x 8 rows = 128 rows/pass, 2 passes.
    const int wid = tid >> 6;
    const int r8  = lane >> 3;   // row within the wave's octet
    const int d4  = lane & 7;    // float4 quarter of the row

    #pragma unroll
    for (int pass = 0; pass < 2; ++pass) {
        const int lrow = pass * 128 + wid * 8 + r8;
        const int cnt  = hist[lrow];
        const int st   = startx[lrow] - cnt;   // exclusive start

        float4 acc = make_float4(0.f, 0.f, 0.f, 0.f);
        int k = 0;
        for (; k + 3 < cnt; k += 4) {
            // LDS entry reads broadcast across the 8 quarter-lanes of this row
            const int2 e0 = srt[st + k + 0];
            const int2 e1 = srt[st + k + 1];
            const int2 e2 = srt[st + k + 2];
            const int2 e3 = srt[st + k + 3];
            const float4 x0 = *(const float4*)&x[e0.x * DIM + d4 * 4];
            const float4 x1 = *(const float4*)&x[e1.x * DIM + d4 * 4];
            const float4 x2 = *(const float4*)&x[e2.x * DIM + d4 * 4];
            const float4 x3 = *(const float4*)&x[e3.x * DIM + d4 * 4];
            const float v0 = __int_as_float(e0.y);
            const float v1 = __int_as_float(e1.y);
            const float v2 = __int_as_float(e2.y);
            const float v3 = __int_as_float(e3.y);
            acc.x = fmaf(v0, x0.x, acc.x);  acc.y = fmaf(v0, x0.y, acc.y);
            acc.z = fmaf(v0, x0.z, acc.z);  acc.w = fmaf(v0, x0.w, acc.w);
            acc.x = fmaf(v1, x1.x, acc.x);  acc.y = fmaf(v1, x1.y, acc.y);
            acc.z = fmaf(v1, x1.z, acc.z);  acc.w = fmaf(v1, x1.w, acc.w);
            acc.x = fmaf(v2, x2.x, acc.x);  acc.y = fmaf(v2, x2.y, acc.y);
            acc.z = fmaf(v2, x2.z, acc.z);  acc.w = fmaf(v2, x2.w, acc.w);
            acc.x = fmaf(v3, x3.x, acc.x);  acc.y = fmaf(v3, x3.y, acc.y);
            acc.z = fmaf(v3, x3.z, acc.z);  acc.w = fmaf(v3, x3.w, acc.w);
        }
        for (; k < cnt; ++k) {
            const int2 e0 = srt[st + k];
            const float4 x0 = *(const float4*)&x[e0.x * DIM + d4 * 4];
            const float v0 = __int_as_float(e0.y);
            acc.x = fmaf(v0, x0.x, acc.x);  acc.y = fmaf(v0, x0.y, acc.y);
            acc.z = fmaf(v0, x0.z, acc.z);  acc.w = fmaf(v0, x0.w, acc.w);
        }

        const int r = bc * CBR + lrow;
        if (r < N_NODES)
            *(float4*)&out[r * DIM + d4 * 4] = acc;   // covers every row; no out memset
    }

    // fused overflow apply: barrier drains the out stores before any RMW
    __syncthreads();
    int on = *ocount;
    if (on > 0) {
        if (on > OCAP) on = OCAP;
        for (int k = tid; k < on; k += SG_THREADS) {
            const int4 t = overflow[k];
            if ((t.x >> 8) == bc) {
                const float v = __int_as_float(t.z);
                const float* __restrict__ xr = x + (long long)t.y * DIM;
                float* orow = out + (long long)t.x * DIM;
                for (int d = 0; d < DIM; ++d)
                    atomicAdd(&orow[d], v * xr[d]);
            }
        }
    }
}

extern "C" void kernel_launch(void* const* d_in, const int* in_sizes, int n_in,
                              void* d_out, int out_size, void* d_ws, size_t ws_size,
                              hipStream_t stream) {
    const int*   A_rows = (const int*)d_in[0];
    const int*   A_cols = (const int*)d_in[1];
    const float* A_vals = (const float*)d_in[2];
    const float* x      = (const float*)d_in[3];
    float*       out    = (float*)d_out;

    if (d_ws == nullptr || ws_size < WS_NEEDED) {
        // workspace too small: original verified atomic path (needs zeroed out)
        hipMemsetAsync(out, 0, (size_t)out_size * sizeof(float), stream);
        const long long total = (long long)N_EDGES * DIM;
        const int block = 256;
        const long long grid = (total + block - 1) / block;
        spmm_atomic_kernel<<<(dim3)(unsigned)grid, block, 0, stream>>>(
            A_rows, A_cols, A_vals, x, out);
        return;
    }

    char* ws = (char*)d_ws;
    int*  ocount   = (int*)ws;
    int*  gcnt     = (int*)(ws + OFF_GCNT);
    int4* overflow = (int4*)(ws + OFF_OVER);
    int2* region   = (int2*)(ws + OFF_REGION);

    // zero ocount + padded gcnt (25 KB); out fully written by pass 2
    hipMemsetAsync(ws, 0, OFF_OVER, stream);

    spmm_scatter_ws<<<SC_BLOCKS, SC_THREADS, 0, stream>>>(
        A_rows, A_cols, A_vals, gcnt, region, ocount, overflow);

    spmm_sort_gather<<<NBC, SG_THREADS, 0, stream>>>(
        gcnt, region, ocount, overflow, x, out);
}